// Round 1
// baseline (592.702 us; speedup 1.0000x reference)
//
#include <hip/hip_runtime.h>

typedef __bf16 bf16x8 __attribute__((ext_vector_type(8)));
typedef float  f32x4  __attribute__((ext_vector_type(4)));
typedef float  f32x2  __attribute__((ext_vector_type(2)));

#define NNODES   50000
#define DIN      256
#define HEADS    32
#define CDIM     16
#define NH       512          // HEADS*CDIM
#define ERAW     800000
#define SCAN_B   196          // ceil(50000/256)
#define LDSW     280          // padded A-row in bf16: r-stride 140 dw -> 2-way bank alias (free)

__device__ __forceinline__ float b2f(unsigned short u) {
    return __uint_as_float(((unsigned)u) << 16);
}
__device__ __forceinline__ unsigned short f2b(float f) {
    unsigned v = __float_as_uint(f);
    v += 0x7fffu + ((v >> 16) & 1u);           // RNE
    return (unsigned short)(v >> 16);
}

// probe edge_index width: int64 -> odd int32 slots are high words == 0
__global__ void k_detect(const int* __restrict__ ei, int* __restrict__ flag) {
    if (threadIdx.x == 0 && blockIdx.x == 0) {
        int nz = 0;
        #pragma unroll
        for (int t = 0; t < 64; ++t) nz |= ei[2 * t + 1];
        flag[0] = (nz == 0) ? 1 : 0;           // 1 => int64
    }
}

// ---------------- CSR build (dst-sorted), raw edges only ----------------
__global__ void k_zero_deg(int* __restrict__ deg) {
    int i = blockIdx.x * 256 + threadIdx.x;
    if (i < NNODES) deg[i] = 0;
}

__global__ void k_hist(const int* __restrict__ ei, const int* __restrict__ flag,
                       int* __restrict__ deg) {
    int e = blockIdx.x * 256 + threadIdx.x;    // exactly 800000
    int d = flag[0] ? ei[2 * ERAW + 2 * e] : ei[ERAW + e];
    atomicAdd(&deg[d], 1);
}

__global__ void k_scan_blk(const int* __restrict__ deg, int* __restrict__ part,
                           int* __restrict__ bsum) {
    __shared__ int sm[256];
    int b = blockIdx.x, t = threadIdx.x, i = b * 256 + t;
    int v = (i < NNODES) ? deg[i] : 0;
    sm[t] = v; __syncthreads();
    for (int off = 1; off < 256; off <<= 1) {
        int u = (t >= off) ? sm[t - off] : 0;
        __syncthreads();
        sm[t] += u; __syncthreads();
    }
    if (i < NNODES) part[i] = sm[t] - v;
    if (t == 255) bsum[b] = sm[255];
}

__global__ void k_scan_top(int* __restrict__ bsum) {
    __shared__ int sm[256];
    int t = threadIdx.x;
    int v = (t < SCAN_B) ? bsum[t] : 0;
    sm[t] = v; __syncthreads();
    for (int off = 1; off < 256; off <<= 1) {
        int u = (t >= off) ? sm[t - off] : 0;
        __syncthreads();
        sm[t] += u; __syncthreads();
    }
    if (t < SCAN_B) bsum[t] = sm[t] - v;
}

__global__ void k_scan_add(const int* __restrict__ part, const int* __restrict__ bsum,
                           int* __restrict__ rs, int* __restrict__ cur) {
    int b = blockIdx.x, t = threadIdx.x, i = b * 256 + t;
    if (i < NNODES) { int r = part[i] + bsum[b]; rs[i] = r; cur[i] = r; }
}

__global__ void k_scatter(const int* __restrict__ ei, const int* __restrict__ flag,
                          int* __restrict__ cur, int* __restrict__ csr) {
    int e = blockIdx.x * 256 + threadIdx.x;    // exactly 800000
    int s, d;
    if (flag[0]) { s = ei[2 * e]; d = ei[2 * ERAW + 2 * e]; }
    else         { s = ei[e];     d = ei[ERAW + e]; }
    int pos = atomicAdd(&cur[d], 1);
    csr[pos] = s;
}

// ---------------- dense compute ----------------
// xb = bf16(x), one pass
__global__ void k_cast_x(const float* __restrict__ x, unsigned short* __restrict__ xb) {
    int i = blockIdx.x * 256 + threadIdx.x;    // 3,200,000 float4 groups
    float4 v = *(const float4*)(x + (size_t)i * 4);
    ushort4 o;
    o.x = f2b(v.x); o.y = f2b(v.y); o.z = f2b(v.z); o.w = f2b(v.w);
    *(ushort4*)(xb + (size_t)i * 4) = o;
}

// dst[n*K+k] = bf16(src[k*N+n]); grid: N blocks, K threads  (plain, for MLP weights)
__global__ void k_tr(const float* __restrict__ src, unsigned short* __restrict__ dst,
                     int K, int N) {
    int n = blockIdx.x, k = threadIdx.x;
    dst[n * K + k] = f2b(src[k * N + n]);
}

// GAT weight transpose with column permutation pi:
// pi(n) = (n & ~63) | ((n&15)*4 + ((n>>4)&3)).
// With this permutation, k_gemm_xp's unchanged epilogue write pattern produces
// xp8 rows that are plain row-major [HEADS][CDIM] fp8 (byte offset = h*16 + c).
__global__ void k_tr_gat(const float* __restrict__ src, unsigned short* __restrict__ dst) {
    int n = blockIdx.x, k = threadIdx.x;       // n in [0,512), k in [0,256)
    int p = (n & ~63) | (((n & 15) << 2) | ((n >> 4) & 3));
    dst[n * DIN + k] = f2b(src[k * NH + p]);
}

// xp8 = fp8_e4m3(xb @ Wt^T). With Wt's pi-permuted columns, the byte at
// row*512 + ch*256 + w*64 + r*4 + t holds true col ch*256+w*64+r*4+t = h*16+c:
// row-major [32][16] fp8 per node. Block: 64 rows x 512 cols (4 waves).
__global__ void __launch_bounds__(256)
k_gemm_xp(const unsigned short* __restrict__ xb,
          const unsigned short* __restrict__ Wt,
          unsigned* __restrict__ xp8) {
    __shared__ unsigned short As[64 * LDSW];
    int row0 = blockIdx.x * 64;                // 782 blocks
    int tid = threadIdx.x;
    int w = tid >> 6, lane = tid & 63;
    int r = lane & 15, quad = lane >> 4;

    {   // stage 64 rows x 256 bf16 (512 B = 32 uint4 per row); 4 threads/row x 8 uint4
        int row = tid >> 2, slot = tid & 3;
        const uint4* g = (const uint4*)(xb + (size_t)(row0 + row) * DIN);
        uint4* l = (uint4*)(As + row * LDSW);  // 560 B stride, 16B-aligned
        #pragma unroll
        for (int i = 0; i < 8; ++i)
            l[slot + 4 * i] = g[slot + 4 * i];
    }
    __syncthreads();

    #pragma unroll
    for (int ch = 0; ch < 2; ++ch) {           // col halves: 256 cols each
        f32x4 acc[4][4] = {};
        #pragma unroll
        for (int kc = 0; kc < 8; ++kc) {
            bf16x8 a[4], b[4];
            #pragma unroll
            for (int sub = 0; sub < 4; ++sub)
                a[sub] = *(const bf16x8*)(As + (sub * 16 + r) * LDSW + kc * 32 + quad * 8);
            #pragma unroll
            for (int t = 0; t < 4; ++t) {
                int col = ch * 256 + w * 64 + t * 16 + r;
                b[t] = *(const bf16x8*)(Wt + (size_t)col * DIN + kc * 32 + quad * 8);
            }
            #pragma unroll
            for (int t = 0; t < 4; ++t)
                #pragma unroll
                for (int sub = 0; sub < 4; ++sub)
                    acc[sub][t] = __builtin_amdgcn_mfma_f32_16x16x32_bf16(a[sub], b[t], acc[sub][t], 0, 0, 0);
        }
        #pragma unroll
        for (int sub = 0; sub < 4; ++sub) {
            #pragma unroll
            for (int j = 0; j < 4; ++j) {
                int row = row0 + sub * 16 + quad * 4 + j;
                if (row < NNODES) {
                    unsigned u = (unsigned)__builtin_amdgcn_cvt_pk_fp8_f32(
                                     acc[sub][0][j], acc[sub][1][j], 0, false);
                    u = (unsigned)__builtin_amdgcn_cvt_pk_fp8_f32(
                                     acc[sub][2][j], acc[sub][3][j], (int)u, true);
                    xp8[(size_t)row * 128 + ch * 64 + w * 16 + r] = u;
                }
            }
        }
    }
}

// a_s[n,h] = sum_c xp[n,h,c]*att_src[h,c] on the row-major fp8 layout.
// One wave per node; lane pair (2h, 2h+1) covers head h's 16 channels.
__global__ void k_att(const unsigned* __restrict__ xp8,
                      const float* __restrict__ att_src,
                      const float* __restrict__ att_dst,
                      float* __restrict__ a_s, float* __restrict__ a_d) {
    int tid = threadIdx.x;
    int nd = blockIdx.x * 4 + (tid >> 6);      // exactly 50000
    int ln = tid & 63;
    int h = ln >> 1;

    const uint2 q = *(const uint2*)(xp8 + (size_t)nd * 128 + ln * 2);
    f32x2 p0 = __builtin_amdgcn_cvt_pk_f32_fp8((int)q.x, false);
    f32x2 p1 = __builtin_amdgcn_cvt_pk_f32_fp8((int)q.x, true);
    f32x2 p2 = __builtin_amdgcn_cvt_pk_f32_fp8((int)q.y, false);
    f32x2 p3 = __builtin_amdgcn_cvt_pk_f32_fp8((int)q.y, true);
    float f[8] = {p0.x, p0.y, p1.x, p1.y, p2.x, p2.y, p3.x, p3.y};

    // channels c0..c0+7 with c0 = 8*(ln&1); coeff base float index = 8*ln
    const f32x4* As4 = (const f32x4*)att_src;
    const f32x4* Ad4 = (const f32x4*)att_dst;
    f32x4 s0 = As4[ln * 2], s1 = As4[ln * 2 + 1];
    f32x4 d0 = Ad4[ln * 2], d1 = Ad4[ln * 2 + 1];

    float ps = f[0]*s0.x + f[1]*s0.y + f[2]*s0.z + f[3]*s0.w
             + f[4]*s1.x + f[5]*s1.y + f[6]*s1.z + f[7]*s1.w;
    float pd = f[0]*d0.x + f[1]*d0.y + f[2]*d0.z + f[3]*d0.w
             + f[4]*d1.x + f[5]*d1.y + f[6]*d1.z + f[7]*d1.w;

    ps += __shfl_xor(ps, 1, 64);
    pd += __shfl_xor(pd, 1, 64);
    if ((ln & 1) == 0) a_s[nd * HEADS + h] = ps;
    else               a_d[nd * HEADS + h] = pd;
}

// One wave per dst node; head-per-lane, 2 edges per iteration (one per half-wave).
// No cross-lane ops in the edge loop.
__global__ void k_conv(const int* __restrict__ csr, const int* __restrict__ rs,
                       const int* __restrict__ deg,
                       const unsigned* __restrict__ xp8,
                       const float* __restrict__ a_s, const float* __restrict__ a_d,
                       const float* __restrict__ bias, float* __restrict__ out) {
    int nd = blockIdx.x * 4 + (threadIdx.x >> 6);      // exactly 50000
    int ln = threadIdx.x & 63;
    int h    = ln & 31;                                // this lane's head
    int half = ln >> 5;                                // edge slot within a pair
    float adn = a_d[nd * HEADS + h];
    int beg = __builtin_amdgcn_readfirstlane(rs[nd]);
    int cnt = __builtin_amdgcn_readfirstlane(deg[nd]);
    const uint4* xv = (const uint4*)xp8;               // 32 uint4 per row; [h] = 16 ch

    float denom = 0.f;
    float acc[16];
    #pragma unroll
    for (int c = 0; c < 16; ++c) acc[c] = 0.f;

    #define EDGE_BODY(AV, QV, LIVE)                                        \
    {                                                                      \
        float tt = (AV) + adn;                                             \
        tt = fmaxf(tt, 0.2f * tt);                                         \
        float e = __expf(tt);                                              \
        e = (LIVE) ? e : 0.f;                                              \
        denom += e;                                                        \
        f32x2 p0 = __builtin_amdgcn_cvt_pk_f32_fp8((int)(QV).x, false);    \
        f32x2 p1 = __builtin_amdgcn_cvt_pk_f32_fp8((int)(QV).x, true);     \
        f32x2 p2 = __builtin_amdgcn_cvt_pk_f32_fp8((int)(QV).y, false);    \
        f32x2 p3 = __builtin_amdgcn_cvt_pk_f32_fp8((int)(QV).y, true);     \
        f32x2 p4 = __builtin_amdgcn_cvt_pk_f32_fp8((int)(QV).z, false);    \
        f32x2 p5 = __builtin_amdgcn_cvt_pk_f32_fp8((int)(QV).z, true);     \
        f32x2 p6 = __builtin_amdgcn_cvt_pk_f32_fp8((int)(QV).w, false);    \
        f32x2 p7 = __builtin_amdgcn_cvt_pk_f32_fp8((int)(QV).w, true);     \
        acc[0]  += e * p0.x; acc[1]  += e * p0.y;                          \
        acc[2]  += e * p1.x; acc[3]  += e * p1.y;                          \
        acc[4]  += e * p2.x; acc[5]  += e * p2.y;                          \
        acc[6]  += e * p3.x; acc[7]  += e * p3.y;                          \
        acc[8]  += e * p4.x; acc[9]  += e * p4.y;                          \
        acc[10] += e * p5.x; acc[11] += e * p5.y;                          \
        acc[12] += e * p6.x; acc[13] += e * p6.y;                          \
        acc[14] += e * p7.x; acc[15] += e * p7.y;                          \
    }

    {   // self contribution (half 0 live, half 1 masked)
        float av = a_s[nd * HEADS + h];
        uint4 qv = xv[(size_t)nd * 32 + h];
        EDGE_BODY(av, qv, half == 0)
    }

    int i = 0;
    for (; i + 8 <= cnt; i += 8) {             // 8 edges = 4 iterations of 2
        int sv[4]; float av[4]; uint4 qv[4];
        #pragma unroll
        for (int k = 0; k < 4; ++k) sv[k] = csr[beg + i + 2 * k + half];
        #pragma unroll
        for (int k = 0; k < 4; ++k) av[k] = a_s[sv[k] * HEADS + h];
        #pragma unroll
        for (int k = 0; k < 4; ++k) qv[k] = xv[(size_t)sv[k] * 32 + h];
        __builtin_amdgcn_sched_barrier(0);     // keep the load batch ahead of compute
        #pragma unroll
        for (int k = 0; k < 4; ++k) EDGE_BODY(av[k], qv[k], 1)
    }
    for (; i < cnt; i += 2) {
        int idx = i + half;
        int ce = idx < cnt ? idx : cnt - 1;    // cnt >= 1 here
        int s = csr[beg + ce];
        float av = a_s[s * HEADS + h];
        uint4 qv = xv[(size_t)s * 32 + h];
        EDGE_BODY(av, qv, idx < cnt)
    }
    #undef EDGE_BODY

    // combine the two half-wave denoms for this head, normalize
    denom += __shfl_xor(denom, 32, 64);
    float inv = 1.f / (denom + 1e-16f);
    #pragma unroll
    for (int c = 0; c < 16; ++c) acc[c] *= inv;

    // transpose-reduce over heads: levels on lane bits 0..3 halve the value
    // count 16->1; levels 4,5 complete the 64-lane sum.
    #pragma unroll
    for (int lv = 0; lv < 4; ++lv) {
        const int mask = 1 << lv;
        const int nv = 16 >> (lv + 1);
        bool hi = (ln & mask) != 0;
        #pragma unroll
        for (int c = 0; c < nv; ++c) {
            float keep = hi ? acc[c + nv] : acc[c];
            float give = hi ? acc[c]      : acc[c + nv];
            acc[c] = keep + __shfl_xor(give, mask, 64);
        }
    }
    acc[0] += __shfl_xor(acc[0], 16, 64);
    acc[0] += __shfl_xor(acc[0], 32, 64);

    if (ln < 16) {
        int c = ((ln & 1) << 3) | ((ln & 2) << 1) | ((ln & 4) >> 1) | ((ln & 8) >> 3);
        float o = acc[0] * (1.0f / HEADS) + bias[c];
        out[(size_t)nd * CDIM + c] = o > 0.f ? o : expm1f(o);
    }
}

// x1 = elu(xb @ w1t + b1); wave = 64 rows x 64 cols; 782 active waves
__global__ void k_mlp1(const unsigned short* __restrict__ xb,
                       const unsigned short* __restrict__ w1t,
                       const float* __restrict__ bb1, unsigned short* __restrict__ x1) {
    int wave = blockIdx.x * 4 + (threadIdx.x >> 6);
    if (wave >= 782) return;
    int lane = threadIdx.x & 63;
    int r = lane & 15, quad = lane >> 4;
    int row0 = wave * 64;

    f32x4 acc[4][4] = {};
    #pragma unroll
    for (int kc = 0; kc < 8; ++kc) {
        bf16x8 a[4];
        #pragma unroll
        for (int sub = 0; sub < 4; ++sub) {
            int row = row0 + sub * 16 + r;
            if (row0 + sub * 16 < NNODES)
                a[sub] = *(const bf16x8*)(xb + (size_t)row * DIN + kc * 32 + quad * 8);
            else {
                union { unsigned short u[8]; bf16x8 v; } z;
                #pragma unroll
                for (int j = 0; j < 8; ++j) z.u[j] = 0;
                a[sub] = z.v;
            }
        }
        #pragma unroll
        for (int t = 0; t < 4; ++t) {
            int col = t * 16 + r;
            bf16x8 b = *(const bf16x8*)(w1t + (size_t)col * DIN + kc * 32 + quad * 8);
            #pragma unroll
            for (int sub = 0; sub < 4; ++sub)
                acc[sub][t] = __builtin_amdgcn_mfma_f32_16x16x32_bf16(a[sub], b, acc[sub][t], 0, 0, 0);
        }
    }
    #pragma unroll
    for (int sub = 0; sub < 4; ++sub) {
        #pragma unroll
        for (int t = 0; t < 4; ++t) {
            int col = t * 16 + r;
            float bv = bb1[col];
            #pragma unroll
            for (int j = 0; j < 4; ++j) {
                int row = row0 + sub * 16 + quad * 4 + j;
                if (row < NNODES) {
                    float v = acc[sub][t][j] + bv;
                    v = v > 0.f ? v : expm1f(v);
                    x1[(size_t)row * 64 + col] = f2b(v);
                }
            }
        }
    }
}

// out = elu(x1 @ w2t + b2); wave = 16 rows x 16 cols; 3125 active waves
__global__ void k_mlp2(const unsigned short* __restrict__ x1,
                       const unsigned short* __restrict__ w2t,
                       const float* __restrict__ bb2, float* __restrict__ out) {
    int wave = blockIdx.x * 4 + (threadIdx.x >> 6);
    if (wave >= 3125) return;
    int lane = threadIdx.x & 63;
    int r = lane & 15, quad = lane >> 4;

    f32x4 acc = {};
    #pragma unroll
    for (int kc = 0; kc < 2; ++kc) {
        bf16x8 a = *(const bf16x8*)(x1 + (size_t)(wave * 16 + r) * 64 + kc * 32 + quad * 8);
        bf16x8 b = *(const bf16x8*)(w2t + (size_t)r * 64 + kc * 32 + quad * 8);
        acc = __builtin_amdgcn_mfma_f32_16x16x32_bf16(a, b, acc, 0, 0, 0);
    }
    float bv = bb2[r];
    #pragma unroll
    for (int j = 0; j < 4; ++j) {
        int row = wave * 16 + quad * 4 + j;
        float v = acc[j] + bv;
        v = v > 0.f ? v : expm1f(v);
        out[(size_t)row * CDIM + r] = v;
    }
}

extern "C" void kernel_launch(void* const* d_in, const int* in_sizes, int n_in,
                              void* d_out, int out_size, void* d_ws, size_t ws_size,
                              hipStream_t stream) {
    const float* x  = (const float*)d_in[0];
    const int* ei   = (const int*)d_in[1];
    const float* W[2]    = {(const float*)d_in[2], (const float*)d_in[6]};
    const float* atS[2]  = {(const float*)d_in[3], (const float*)d_in[7]};
    const float* atD[2]  = {(const float*)d_in[4], (const float*)d_in[8]};
    const float* bias[2] = {(const float*)d_in[5], (const float*)d_in[9]};
    const float* w1 = (const float*)d_in[10];
    const float* b1 = (const float*)d_in[11];
    const float* w2 = (const float*)d_in[12];
    const float* b2 = (const float*)d_in[13];
    float* out = (float*)d_out;

    char* ws = (char*)d_ws;
    unsigned* xp8 = (unsigned*)(ws);                          // 25,600,000 B
    unsigned short* xb  = (unsigned short*)(ws + 25600000);   // 25,600,000 B
    unsigned short* Wt  = (unsigned short*)(ws + 51200000);   //    262,144 B (xb tail-read spills here: benign bf16)
    unsigned short* w1t = (unsigned short*)(ws + 51462144);   //     32,768 B
    unsigned short* w2t = (unsigned short*)(ws + 51494912);   //      2,048 B
    float* a_s = (float*)(ws + 51496960);                     //  6,400,000 B
    float* a_d = (float*)(ws + 57896960);                     //  6,400,000 B
    unsigned short* x1 = (unsigned short*)(ws + 51496960);    // alias a_s (dead before mlp1)
    int* deg   = (int*)(ws + 64296960);                       //    200,000 B
    int* rs    = (int*)(ws + 64496960);                       //    200,000 B
    int* cur   = (int*)(ws + 64696960);                       //    200,000 B
    int* part  = (int*)(ws + 64896960);                       //    200,000 B
    int* bsum  = (int*)(ws + 65096960);                       //      1,024 B
    int* csr   = (int*)(ws + 65097984);                       //  3,200,000 B
    int* flag  = (int*)(ws + 68297984);                       //          4 B

    k_detect<<<1, 64, 0, stream>>>(ei, flag);
    k_zero_deg<<<SCAN_B, 256, 0, stream>>>(deg);
    k_hist    <<<3125, 256, 0, stream>>>(ei, flag, deg);
    k_scan_blk<<<SCAN_B, 256, 0, stream>>>(deg, part, bsum);
    k_scan_top<<<1, 256, 0, stream>>>(bsum);
    k_scan_add<<<SCAN_B, 256, 0, stream>>>(part, bsum, rs, cur);
    k_scatter <<<3125, 256, 0, stream>>>(ei, flag, cur, csr);

    k_cast_x<<<12500, 256, 0, stream>>>(x, xb);
    k_tr<<<64, 256, 0, stream>>>(w1, w1t, DIN, 64);
    k_tr<<<16, 64, 0, stream>>>(w2, w2t, 64, CDIM);

    for (int cv = 0; cv < 2; ++cv) {
        k_tr_gat <<<512, 256, 0, stream>>>(W[cv], Wt);
        k_gemm_xp<<<782, 256, 0, stream>>>(xb, Wt, xp8);
        k_att    <<<12500, 256, 0, stream>>>(xp8, atS[cv], atD[cv], a_s, a_d);
        k_conv   <<<12500, 256, 0, stream>>>(csr, rs, deg, xp8, a_s, a_d,
                                             bias[cv], out + (size_t)cv * 800000);
    }
    k_mlp1<<<196, 256, 0, stream>>>(xb, w1t, b1, x1);
    k_mlp2<<<782, 256, 0, stream>>>(x1, w2t, b2, out + 1600000);
}

// Round 2
// 498.313 us; speedup vs baseline: 1.1894x; 1.1894x over previous
//
#include <hip/hip_runtime.h>

typedef __bf16 bf16x8 __attribute__((ext_vector_type(8)));
typedef float  f32x4  __attribute__((ext_vector_type(4)));
typedef float  f32x2  __attribute__((ext_vector_type(2)));

#define NNODES   50000
#define DIN      256
#define HEADS    32
#define CDIM     16
#define NH       512          // HEADS*CDIM
#define ERAW     800000
#define SCAN_B   196          // ceil(50000/256)
#define LDSW     280          // padded A-row in bf16: r-stride 140 dw -> 2-way bank alias (free)

__device__ __forceinline__ float b2f(unsigned short u) {
    return __uint_as_float(((unsigned)u) << 16);
}
__device__ __forceinline__ unsigned short f2b(float f) {
    unsigned v = __float_as_uint(f);
    v += 0x7fffu + ((v >> 16) & 1u);           // RNE
    return (unsigned short)(v >> 16);
}

// probe edge_index width: int64 -> odd int32 slots are high words == 0
__global__ void k_detect(const int* __restrict__ ei, int* __restrict__ flag) {
    if (threadIdx.x == 0 && blockIdx.x == 0) {
        int nz = 0;
        #pragma unroll
        for (int t = 0; t < 64; ++t) nz |= ei[2 * t + 1];
        flag[0] = (nz == 0) ? 1 : 0;           // 1 => int64
    }
}

// ---------------- CSR build (dst-sorted), raw edges only ----------------
__global__ void k_zero_deg(int* __restrict__ deg) {
    int i = blockIdx.x * 256 + threadIdx.x;
    if (i < NNODES) deg[i] = 0;
}

__global__ void k_hist(const int* __restrict__ ei, const int* __restrict__ flag,
                       int* __restrict__ deg) {
    int e = blockIdx.x * 256 + threadIdx.x;    // exactly 800000
    int d = flag[0] ? ei[2 * ERAW + 2 * e] : ei[ERAW + e];
    atomicAdd(&deg[d], 1);
}

__global__ void k_scan_blk(const int* __restrict__ deg, int* __restrict__ part,
                           int* __restrict__ bsum) {
    __shared__ int sm[256];
    int b = blockIdx.x, t = threadIdx.x, i = b * 256 + t;
    int v = (i < NNODES) ? deg[i] : 0;
    sm[t] = v; __syncthreads();
    for (int off = 1; off < 256; off <<= 1) {
        int u = (t >= off) ? sm[t - off] : 0;
        __syncthreads();
        sm[t] += u; __syncthreads();
    }
    if (i < NNODES) part[i] = sm[t] - v;
    if (t == 255) bsum[b] = sm[255];
}

__global__ void k_scan_top(int* __restrict__ bsum) {
    __shared__ int sm[256];
    int t = threadIdx.x;
    int v = (t < SCAN_B) ? bsum[t] : 0;
    sm[t] = v; __syncthreads();
    for (int off = 1; off < 256; off <<= 1) {
        int u = (t >= off) ? sm[t - off] : 0;
        __syncthreads();
        sm[t] += u; __syncthreads();
    }
    if (t < SCAN_B) bsum[t] = sm[t] - v;
}

__global__ void k_scan_add(const int* __restrict__ part, const int* __restrict__ bsum,
                           int* __restrict__ rs, int* __restrict__ cur) {
    int b = blockIdx.x, t = threadIdx.x, i = b * 256 + t;
    if (i < NNODES) { int r = part[i] + bsum[b]; rs[i] = r; cur[i] = r; }
}

__global__ void k_scatter(const int* __restrict__ ei, const int* __restrict__ flag,
                          int* __restrict__ cur, int* __restrict__ csr) {
    int e = blockIdx.x * 256 + threadIdx.x;    // exactly 800000
    int s, d;
    if (flag[0]) { s = ei[2 * e]; d = ei[2 * ERAW + 2 * e]; }
    else         { s = ei[e];     d = ei[ERAW + e]; }
    int pos = atomicAdd(&cur[d], 1);
    csr[pos] = s;
}

// ---------------- dense compute ----------------
// xb = bf16(x), one pass
__global__ void k_cast_x(const float* __restrict__ x, unsigned short* __restrict__ xb) {
    int i = blockIdx.x * 256 + threadIdx.x;    // 3,200,000 float4 groups
    float4 v = *(const float4*)(x + (size_t)i * 4);
    ushort4 o;
    o.x = f2b(v.x); o.y = f2b(v.y); o.z = f2b(v.z); o.w = f2b(v.w);
    *(ushort4*)(xb + (size_t)i * 4) = o;
}

// dst[n*K+k] = bf16(src[k*N+n]); grid: N blocks, K threads  (plain, for MLP weights)
__global__ void k_tr(const float* __restrict__ src, unsigned short* __restrict__ dst,
                     int K, int N) {
    int n = blockIdx.x, k = threadIdx.x;
    dst[n * K + k] = f2b(src[k * N + n]);
}

// GAT weight transpose with column permutation pi:
// pi(n) = (n & ~63) | ((n&15)*4 + ((n>>4)&3)).
// With this permutation, k_gemm_xp's unchanged epilogue write pattern produces
// xp8 rows that are plain row-major [HEADS][CDIM] fp8 (byte offset = h*16 + c).
__global__ void k_tr_gat(const float* __restrict__ src, unsigned short* __restrict__ dst) {
    int n = blockIdx.x, k = threadIdx.x;       // n in [0,512), k in [0,256)
    int p = (n & ~63) | (((n & 15) << 2) | ((n >> 4) & 3));
    dst[n * DIN + k] = f2b(src[k * NH + p]);
}

// xp8 = fp8_e4m3(xb @ Wt^T). With Wt's pi-permuted columns, the byte at
// row*512 + ch*256 + w*64 + r*4 + t holds true col ch*256+w*64+r*4+t = h*16+c:
// row-major [32][16] fp8 per node. Block: 64 rows x 512 cols (4 waves).
__global__ void __launch_bounds__(256)
k_gemm_xp(const unsigned short* __restrict__ xb,
          const unsigned short* __restrict__ Wt,
          unsigned* __restrict__ xp8) {
    __shared__ unsigned short As[64 * LDSW];
    int row0 = blockIdx.x * 64;                // 782 blocks
    int tid = threadIdx.x;
    int w = tid >> 6, lane = tid & 63;
    int r = lane & 15, quad = lane >> 4;

    {   // stage 64 rows x 256 bf16 (512 B = 32 uint4 per row); 4 threads/row x 8 uint4
        int row = tid >> 2, slot = tid & 3;
        const uint4* g = (const uint4*)(xb + (size_t)(row0 + row) * DIN);
        uint4* l = (uint4*)(As + row * LDSW);  // 560 B stride, 16B-aligned
        #pragma unroll
        for (int i = 0; i < 8; ++i)
            l[slot + 4 * i] = g[slot + 4 * i];
    }
    __syncthreads();

    #pragma unroll
    for (int ch = 0; ch < 2; ++ch) {           // col halves: 256 cols each
        f32x4 acc[4][4] = {};
        #pragma unroll
        for (int kc = 0; kc < 8; ++kc) {
            bf16x8 a[4], b[4];
            #pragma unroll
            for (int sub = 0; sub < 4; ++sub)
                a[sub] = *(const bf16x8*)(As + (sub * 16 + r) * LDSW + kc * 32 + quad * 8);
            #pragma unroll
            for (int t = 0; t < 4; ++t) {
                int col = ch * 256 + w * 64 + t * 16 + r;
                b[t] = *(const bf16x8*)(Wt + (size_t)col * DIN + kc * 32 + quad * 8);
            }
            #pragma unroll
            for (int t = 0; t < 4; ++t)
                #pragma unroll
                for (int sub = 0; sub < 4; ++sub)
                    acc[sub][t] = __builtin_amdgcn_mfma_f32_16x16x32_bf16(a[sub], b[t], acc[sub][t], 0, 0, 0);
        }
        #pragma unroll
        for (int sub = 0; sub < 4; ++sub) {
            #pragma unroll
            for (int j = 0; j < 4; ++j) {
                int row = row0 + sub * 16 + quad * 4 + j;
                if (row < NNODES) {
                    unsigned u = (unsigned)__builtin_amdgcn_cvt_pk_fp8_f32(
                                     acc[sub][0][j], acc[sub][1][j], 0, false);
                    u = (unsigned)__builtin_amdgcn_cvt_pk_fp8_f32(
                                     acc[sub][2][j], acc[sub][3][j], (int)u, true);
                    xp8[(size_t)row * 128 + ch * 64 + w * 16 + r] = u;
                }
            }
        }
    }
}

// a_s[n,h] = sum_c xp[n,h,c]*att_src[h,c] on the row-major fp8 layout.
// One wave per node; lane pair (2h, 2h+1) covers head h's 16 channels.
__global__ void k_att(const unsigned* __restrict__ xp8,
                      const float* __restrict__ att_src,
                      const float* __restrict__ att_dst,
                      float* __restrict__ a_s, float* __restrict__ a_d) {
    int tid = threadIdx.x;
    int nd = blockIdx.x * 4 + (tid >> 6);      // exactly 50000
    int ln = tid & 63;
    int h = ln >> 1;

    const uint2 q = *(const uint2*)(xp8 + (size_t)nd * 128 + ln * 2);
    f32x2 p0 = __builtin_amdgcn_cvt_pk_f32_fp8((int)q.x, false);
    f32x2 p1 = __builtin_amdgcn_cvt_pk_f32_fp8((int)q.x, true);
    f32x2 p2 = __builtin_amdgcn_cvt_pk_f32_fp8((int)q.y, false);
    f32x2 p3 = __builtin_amdgcn_cvt_pk_f32_fp8((int)q.y, true);
    float f[8] = {p0.x, p0.y, p1.x, p1.y, p2.x, p2.y, p3.x, p3.y};

    // channels c0..c0+7 with c0 = 8*(ln&1); coeff base float index = 8*ln
    const f32x4* As4 = (const f32x4*)att_src;
    const f32x4* Ad4 = (const f32x4*)att_dst;
    f32x4 s0 = As4[ln * 2], s1 = As4[ln * 2 + 1];
    f32x4 d0 = Ad4[ln * 2], d1 = Ad4[ln * 2 + 1];

    float ps = f[0]*s0.x + f[1]*s0.y + f[2]*s0.z + f[3]*s0.w
             + f[4]*s1.x + f[5]*s1.y + f[6]*s1.z + f[7]*s1.w;
    float pd = f[0]*d0.x + f[1]*d0.y + f[2]*d0.z + f[3]*d0.w
             + f[4]*d1.x + f[5]*d1.y + f[6]*d1.z + f[7]*d1.w;

    ps += __shfl_xor(ps, 1, 64);
    pd += __shfl_xor(pd, 1, 64);
    if ((ln & 1) == 0) a_s[nd * HEADS + h] = ps;
    else               a_d[nd * HEADS + h] = pd;
}

// One wave per dst node; one edge per wave step (scalar sv -> SGPR-base loads).
// Lane ln owns head ln>>1, channels 8*(ln&1)..+7 (byte offset ln*8 in the row).
// Score is computed per-lane (duplicated on the lane pair): no cross-lane ops
// and no VGPR address math in the edge loop.
__global__ void k_conv(const int* __restrict__ csr, const int* __restrict__ rs,
                       const int* __restrict__ deg,
                       const unsigned* __restrict__ xp8,
                       const float* __restrict__ a_s, const float* __restrict__ a_d,
                       const float* __restrict__ bias, float* __restrict__ out) {
    int nd = blockIdx.x * 4 + (threadIdx.x >> 6);      // exactly 50000
    int ln = threadIdx.x & 63;
    int h  = ln >> 1;                                  // this lane's head
    int cb = (ln & 1) * 8;                             // channel base within head
    float adn = a_d[nd * HEADS + h];
    int beg = __builtin_amdgcn_readfirstlane(rs[nd]);
    int cnt = __builtin_amdgcn_readfirstlane(deg[nd]);
    const uint2* xv = (const uint2*)xp8;               // 64 uint2 per row; lane slot = ln

    float denom = 0.f;
    float acc[8] = {0, 0, 0, 0, 0, 0, 0, 0};

    #define EDGE_BODY(AV, QV)                                              \
    {                                                                      \
        float tt = (AV) + adn;                                             \
        tt = fmaxf(tt, 0.2f * tt);                                         \
        float e = __expf(tt);                                              \
        denom += e;                                                        \
        f32x2 p0 = __builtin_amdgcn_cvt_pk_f32_fp8((int)(QV).x, false);    \
        f32x2 p1 = __builtin_amdgcn_cvt_pk_f32_fp8((int)(QV).x, true);     \
        f32x2 p2 = __builtin_amdgcn_cvt_pk_f32_fp8((int)(QV).y, false);    \
        f32x2 p3 = __builtin_amdgcn_cvt_pk_f32_fp8((int)(QV).y, true);     \
        acc[0] += e * p0.x; acc[1] += e * p0.y;                            \
        acc[2] += e * p1.x; acc[3] += e * p1.y;                            \
        acc[4] += e * p2.x; acc[5] += e * p2.y;                            \
        acc[6] += e * p3.x; acc[7] += e * p3.y;                            \
    }

    {   // self contribution
        float av = a_s[nd * HEADS + h];
        uint2 qv = xv[(size_t)nd * 64 + ln];
        EDGE_BODY(av, qv)
    }

    int i = 0;
    for (; i + 8 <= cnt; i += 8) {
        int sv[8];
        #pragma unroll
        for (int k = 0; k < 8; ++k) sv[k] = csr[beg + i + k];   // uniform -> s_load
        float av[8];
        #pragma unroll
        for (int k = 0; k < 8; ++k) av[k] = a_s[sv[k] * HEADS + h];
        uint2 qv[8];
        #pragma unroll
        for (int k = 0; k < 8; ++k) qv[k] = xv[(size_t)sv[k] * 64 + ln];
        #pragma unroll
        for (int k = 0; k < 8; ++k) EDGE_BODY(av[k], qv[k])
    }
    for (; i < cnt; ++i) {
        int s = csr[beg + i];
        float av = a_s[s * HEADS + h];
        uint2 qv = xv[(size_t)s * 64 + ln];
        EDGE_BODY(av, qv)
    }
    #undef EDGE_BODY

    // normalize this lane's head, then mean over heads: sum across the 32
    // lanes of the same parity (all 32 heads), once per node.
    float inv = 1.f / (denom + 1e-16f);
    #pragma unroll
    for (int c = 0; c < 8; ++c) acc[c] *= inv;

    #pragma unroll
    for (int mask = 2; mask <= 32; mask <<= 1) {
        #pragma unroll
        for (int c = 0; c < 8; ++c) acc[c] += __shfl_xor(acc[c], mask, 64);
    }
    if (ln < 2) {
        #pragma unroll
        for (int c2 = 0; c2 < 8; ++c2) {
            int c = cb + c2;
            float o = acc[c2] * (1.0f / HEADS) + bias[c];
            out[(size_t)nd * CDIM + c] = o > 0.f ? o : expm1f(o);
        }
    }
}

// x1 = elu(xb @ w1t + b1); wave = 64 rows x 64 cols; 782 active waves
__global__ void k_mlp1(const unsigned short* __restrict__ xb,
                       const unsigned short* __restrict__ w1t,
                       const float* __restrict__ bb1, unsigned short* __restrict__ x1) {
    int wave = blockIdx.x * 4 + (threadIdx.x >> 6);
    if (wave >= 782) return;
    int lane = threadIdx.x & 63;
    int r = lane & 15, quad = lane >> 4;
    int row0 = wave * 64;

    f32x4 acc[4][4] = {};
    #pragma unroll
    for (int kc = 0; kc < 8; ++kc) {
        bf16x8 a[4];
        #pragma unroll
        for (int sub = 0; sub < 4; ++sub) {
            int row = row0 + sub * 16 + r;
            if (row0 + sub * 16 < NNODES)
                a[sub] = *(const bf16x8*)(xb + (size_t)row * DIN + kc * 32 + quad * 8);
            else {
                union { unsigned short u[8]; bf16x8 v; } z;
                #pragma unroll
                for (int j = 0; j < 8; ++j) z.u[j] = 0;
                a[sub] = z.v;
            }
        }
        #pragma unroll
        for (int t = 0; t < 4; ++t) {
            int col = t * 16 + r;
            bf16x8 b = *(const bf16x8*)(w1t + (size_t)col * DIN + kc * 32 + quad * 8);
            #pragma unroll
            for (int sub = 0; sub < 4; ++sub)
                acc[sub][t] = __builtin_amdgcn_mfma_f32_16x16x32_bf16(a[sub], b, acc[sub][t], 0, 0, 0);
        }
    }
    #pragma unroll
    for (int sub = 0; sub < 4; ++sub) {
        #pragma unroll
        for (int t = 0; t < 4; ++t) {
            int col = t * 16 + r;
            float bv = bb1[col];
            #pragma unroll
            for (int j = 0; j < 4; ++j) {
                int row = row0 + sub * 16 + quad * 4 + j;
                if (row < NNODES) {
                    float v = acc[sub][t][j] + bv;
                    v = v > 0.f ? v : expm1f(v);
                    x1[(size_t)row * 64 + col] = f2b(v);
                }
            }
        }
    }
}

// out = elu(x1 @ w2t + b2); wave = 16 rows x 16 cols; 3125 active waves
__global__ void k_mlp2(const unsigned short* __restrict__ x1,
                       const unsigned short* __restrict__ w2t,
                       const float* __restrict__ bb2, float* __restrict__ out) {
    int wave = blockIdx.x * 4 + (threadIdx.x >> 6);
    if (wave >= 3125) return;
    int lane = threadIdx.x & 63;
    int r = lane & 15, quad = lane >> 4;

    f32x4 acc = {};
    #pragma unroll
    for (int kc = 0; kc < 2; ++kc) {
        bf16x8 a = *(const bf16x8*)(x1 + (size_t)(wave * 16 + r) * 64 + kc * 32 + quad * 8);
        bf16x8 b = *(const bf16x8*)(w2t + (size_t)r * 64 + kc * 32 + quad * 8);
        acc = __builtin_amdgcn_mfma_f32_16x16x32_bf16(a, b, acc, 0, 0, 0);
    }
    float bv = bb2[r];
    #pragma unroll
    for (int j = 0; j < 4; ++j) {
        int row = wave * 16 + quad * 4 + j;
        float v = acc[j] + bv;
        v = v > 0.f ? v : expm1f(v);
        out[(size_t)row * CDIM + r] = v;
    }
}

extern "C" void kernel_launch(void* const* d_in, const int* in_sizes, int n_in,
                              void* d_out, int out_size, void* d_ws, size_t ws_size,
                              hipStream_t stream) {
    const float* x  = (const float*)d_in[0];
    const int* ei   = (const int*)d_in[1];
    const float* W[2]    = {(const float*)d_in[2], (const float*)d_in[6]};
    const float* atS[2]  = {(const float*)d_in[3], (const float*)d_in[7]};
    const float* atD[2]  = {(const float*)d_in[4], (const float*)d_in[8]};
    const float* bias[2] = {(const float*)d_in[5], (const float*)d_in[9]};
    const float* w1 = (const float*)d_in[10];
    const float* b1 = (const float*)d_in[11];
    const float* w2 = (const float*)d_in[12];
    const float* b2 = (const float*)d_in[13];
    float* out = (float*)d_out;

    char* ws = (char*)d_ws;
    unsigned* xp8 = (unsigned*)(ws);                          // 25,600,000 B
    unsigned short* xb  = (unsigned short*)(ws + 25600000);   // 25,600,000 B
    unsigned short* Wt  = (unsigned short*)(ws + 51200000);   //    262,144 B (xb tail-read spills here: benign bf16)
    unsigned short* w1t = (unsigned short*)(ws + 51462144);   //     32,768 B
    unsigned short* w2t = (unsigned short*)(ws + 51494912);   //      2,048 B
    float* a_s = (float*)(ws + 51496960);                     //  6,400,000 B
    float* a_d = (float*)(ws + 57896960);                     //  6,400,000 B
    unsigned short* x1 = (unsigned short*)(ws + 51496960);    // alias a_s (dead before mlp1)
    int* deg   = (int*)(ws + 64296960);                       //    200,000 B
    int* rs    = (int*)(ws + 64496960);                       //    200,000 B
    int* cur   = (int*)(ws + 64696960);                       //    200,000 B
    int* part  = (int*)(ws + 64896960);                       //    200,000 B
    int* bsum  = (int*)(ws + 65096960);                       //      1,024 B
    int* csr   = (int*)(ws + 65097984);                       //  3,200,000 B
    int* flag  = (int*)(ws + 68297984);                       //          4 B

    k_detect<<<1, 64, 0, stream>>>(ei, flag);
    k_zero_deg<<<SCAN_B, 256, 0, stream>>>(deg);
    k_hist    <<<3125, 256, 0, stream>>>(ei, flag, deg);
    k_scan_blk<<<SCAN_B, 256, 0, stream>>>(deg, part, bsum);
    k_scan_top<<<1, 256, 0, stream>>>(bsum);
    k_scan_add<<<SCAN_B, 256, 0, stream>>>(part, bsum, rs, cur);
    k_scatter <<<3125, 256, 0, stream>>>(ei, flag, cur, csr);

    k_cast_x<<<12500, 256, 0, stream>>>(x, xb);
    k_tr<<<64, 256, 0, stream>>>(w1, w1t, DIN, 64);
    k_tr<<<16, 64, 0, stream>>>(w2, w2t, 64, CDIM);

    for (int cv = 0; cv < 2; ++cv) {
        k_tr_gat <<<512, 256, 0, stream>>>(W[cv], Wt);
        k_gemm_xp<<<782, 256, 0, stream>>>(xb, Wt, xp8);
        k_att    <<<12500, 256, 0, stream>>>(xp8, atS[cv], atD[cv], a_s, a_d);
        k_conv   <<<12500, 256, 0, stream>>>(csr, rs, deg, xp8, a_s, a_d,
                                             bias[cv], out + (size_t)cv * 800000);
    }
    k_mlp1<<<196, 256, 0, stream>>>(xb, w1t, b1, x1);
    k_mlp2<<<782, 256, 0, stream>>>(x1, w2t, b2, out + 1600000);
}